// Round 6
// baseline (287.917 us; speedup 1.0000x reference)
//
#include <hip/hip_runtime.h>

#define NBINS 10
#define ROWW  19         // LDS row stride (dwords): 10 prob + 8 packed cnt/tp + 1 pad (odd stride)
#define PART_STRIDE 32   // per-block partial row stride (padded from 30)

// Round 6: register accumulation (R2/R5-proven) + software-pipelined loads.
// R5 post-mortem: kernel was global-load-latency bound (VALUBusy derived
// counter uses SIMD-16 formula -> real busy ~22%). Fix: for the exact shape
// (16 float4-slots/thread) fully unroll 8 bursts of (2 o4 + 2 l4) loads,
// prefetched one burst ahead, so each burst's ~900cyc compute hides the next
// burst's load latency. Accumulators unchanged:
//  - prob: 10 fp32 regs, predicated add chain.
//  - count/tp: 64-bit 6-bit-field packed, flushed to 12-bit fields every 32.
__global__ __launch_bounds__(256) void calib_hist(
    const float* __restrict__ outputs,
    const float* __restrict__ labels,
    float* __restrict__ partials,
    long n)
{
    __shared__ unsigned int s_lane[256 * ROWW];   // 19456 B
    __shared__ float        s_red[240];           // chunk partials (8 x 30)

    const int tid = threadIdx.x;
    const float low0 = -1e-6f;
    const float step = (1.0f - low0) / 10.0f;     // fp32 linspace delta (const-folded)

    float prob[NBINS];
#pragma unroll
    for (int b = 0; b < NBINS; ++b) prob[b] = 0.0f;
    unsigned long long cnt64 = 0ull, tp64 = 0ull;            // 6-bit fields, bins 0..9
    unsigned long long cntA = 0ull, cntB = 0ull;             // 12-bit fields, bins 0-4 / 5-9
    unsigned long long tpA  = 0ull, tpB  = 0ull;

    auto body = [&](float x, float y) {
        bool valid = (x > low0) & (x <= 1.0f);
        int e = (int)(x * 10.0f);
        e = e < 0 ? 0 : (e > 9 ? 9 : e);
        float fe  = (float)e;
        float hb0 = fmaf(fe,        step, low0);   // high[e-1]
        float hb1 = fmaf(fe + 1.0f, step, low0);   // high[e]
        int b = e + ((x > hb1) ? 1 : 0) - (((e > 0) & (x <= hb0)) ? 1 : 0);
        // b in [0,10]; b==10 only when invalid (x>1) -> inc=0, bits 60-63 unused.
        float px = valid ? x : 0.0f;
        unsigned long long one = (unsigned long long)(valid ? 1u : 0u) << (b * 6);
        cnt64 += one;
        tp64  += (y > 0.5f) ? one : 0ull;
#pragma unroll
        for (int bb = 0; bb < NBINS; ++bb)
            prob[bb] += (b == bb) ? px : 0.0f;
    };

    auto flush = [&]() {
#pragma unroll
        for (int f = 0; f < 5; ++f) {
            cntA += ((cnt64 >> (6 * f))      & 63ull) << (12 * f);
            cntB += ((cnt64 >> (6 * f + 30)) & 63ull) << (12 * f);
            tpA  += ((tp64  >> (6 * f))      & 63ull) << (12 * f);
            tpB  += ((tp64  >> (6 * f + 30)) & 63ull) << (12 * f);
        }
        cnt64 = 0ull; tp64 = 0ull;
    };

    const long total4 = n >> 2;
    const float4* o4 = (const float4*)outputs;
    const float4* l4 = (const float4*)labels;
    const long gid = (long)blockIdx.x * 256 + tid;
    const long gsz = (long)gridDim.x * 256;

    if (total4 == 16 * gsz && (n & 3) == 0) {
        // ---- fast path: exactly 16 float4-slots per thread per array ----
        const float4* op = o4 + gid;
        const float4* lp = l4 + gid;
        float4 oc0 = op[0], oc1 = op[gsz];
        float4 lc0 = lp[0], lc1 = lp[gsz];
#pragma unroll
        for (int k = 0; k < 8; ++k) {
            float4 on0, on1, ln0, ln1;
            if (k < 7) {                       // prefetch next burst
                long s0 = (long)(2 * k + 2) * gsz;
                long s1 = (long)(2 * k + 3) * gsz;
                on0 = op[s0]; on1 = op[s1];
                ln0 = lp[s0]; ln1 = lp[s1];
            }
            body(oc0.x, lc0.x); body(oc0.y, lc0.y);
            body(oc0.z, lc0.z); body(oc0.w, lc0.w);
            body(oc1.x, lc1.x); body(oc1.y, lc1.y);
            body(oc1.z, lc1.z); body(oc1.w, lc1.w);
            if (k == 3) flush();               // 32 elems per 6-bit window
            if (k < 7) { oc0 = on0; oc1 = on1; lc0 = ln0; lc1 = ln1; }
        }
        flush();
    } else {
        // ---- generic fallback (R5 structure) ----
        int since = 0;
        for (long j = gid; j < total4; j += gsz) {
            float4 o = o4[j]; float4 l = l4[j];
            body(o.x, l.x); body(o.y, l.y); body(o.z, l.z); body(o.w, l.w);
            if (++since == 8) { flush(); since = 0; }
        }
        flush();
        const long tail0 = total4 << 2;
        for (long t = tail0 + gid; t < n; t += gsz)
            body(outputs[t], labels[t]);       // <=4 elems, no overflow
        flush();
    }

    // ---- epilogue: one LDS dump per lane, 2-level block reduce ----
    unsigned int* row = &s_lane[tid * ROWW];
#pragma unroll
    for (int b = 0; b < NBINS; ++b) row[b] = __float_as_uint(prob[b]);
    row[10] = (unsigned)cntA; row[11] = (unsigned)(cntA >> 32);
    row[12] = (unsigned)cntB; row[13] = (unsigned)(cntB >> 32);
    row[14] = (unsigned)tpA;  row[15] = (unsigned)(tpA  >> 32);
    row[16] = (unsigned)tpB;  row[17] = (unsigned)(tpB  >> 32);
    __syncthreads();

    // slots: 0-9 prob, 10-19 tp, 20-29 count (matches d_out layout)
    if (tid < 240) {
        int chunk = tid / 30, slot = tid % 30;
        int r0 = chunk * 32;
        float acc = 0.0f;
        if (slot < NBINS) {
            for (int r = r0; r < r0 + 32; ++r)
                acc += __uint_as_float(s_lane[r * ROWW + slot]);
        } else {
            int b   = slot - ((slot < 20) ? 10 : 20);
            int off = ((slot < 20) ? 14 : 10) + ((b < 5) ? 0 : 2);  // tp at 14/16, cnt at 10/12
            int sh  = 12 * ((b < 5) ? b : b - 5);
            for (int r = r0; r < r0 + 32; ++r) {
                unsigned long long w =
                    ((unsigned long long)s_lane[r * ROWW + off + 1] << 32) |
                     (unsigned long long)s_lane[r * ROWW + off];
                acc += (float)((unsigned)((w >> sh) & 4095ull));
            }
        }
        s_red[chunk * 30 + slot] = acc;
    }
    __syncthreads();
    if (tid < 3 * NBINS) {
        float s = 0.0f;
#pragma unroll
        for (int c = 0; c < 8; ++c) s += s_red[c * 30 + tid];
        partials[(long)blockIdx.x * PART_STRIDE + tid] = s;
    }
}

// Kernel 2: one block per output slot; double-precision accumulate of partials.
__global__ __launch_bounds__(256) void calib_reduce(
    const float* __restrict__ partials, float* __restrict__ out, int nrows)
{
    const int s   = blockIdx.x;    // 0..29
    const int tid = threadIdx.x;
    double acc = 0.0;
    for (int r = tid; r < nrows; r += 256)
        acc += (double)partials[(long)r * PART_STRIDE + s];
#pragma unroll
    for (int off = 32; off > 0; off >>= 1)
        acc += __shfl_down(acc, off, 64);
    __shared__ double wsum[4];
    if ((tid & 63) == 0) wsum[tid >> 6] = acc;
    __syncthreads();
    if (tid == 0) out[s] = (float)(wsum[0] + wsum[1] + wsum[2] + wsum[3]);
}

extern "C" void kernel_launch(void* const* d_in, const int* in_sizes, int n_in,
                              void* d_out, int out_size, void* d_ws, size_t ws_size,
                              hipStream_t stream) {
    const float* outputs = (const float*)d_in[0];
    const float* labels  = (const float*)d_in[1];
    float* out = (float*)d_out;
    long n = (long)in_sizes[0];

    // 2048 blocks = 8/CU; 64 elems/thread (16 float4-slots -> fast path).
    int nblocks = 2048;
    size_t need = (size_t)nblocks * PART_STRIDE * sizeof(float);
    if (ws_size < need) {
        nblocks = (int)(ws_size / (PART_STRIDE * sizeof(float)));
        if (nblocks < 1) nblocks = 1;
    }
    float* partials = (float*)d_ws;

    calib_hist  <<<nblocks, 256, 0, stream>>>(outputs, labels, partials, n);
    calib_reduce<<<3 * NBINS, 256, 0, stream>>>(partials, out, nblocks);
}